// Round 2
// baseline (422.102 us; speedup 1.0000x reference)
//
#include <hip/hip_runtime.h>

#define EMBED_D 128
#define KNBR 50
#define MROWS 64      // padded neighbor rows for 16-row MFMA tiles
#define XSTR 264      // X row stride in bf16 elems (256 + 8 pad)
#define NSTR 136      // nbr row stride in bf16 elems (128 + 8 pad)

typedef __attribute__((ext_vector_type(8))) short short8;    // 8 bf16 = 4 VGPRs (MFMA A/B frag)
typedef __attribute__((ext_vector_type(4))) float floatx4;   // MFMA C/D frag

__device__ __forceinline__ float b2f(unsigned short u) {
    union { unsigned int i; float f; } v;
    v.i = ((unsigned int)u) << 16;
    return v.f;
}
__device__ __forceinline__ unsigned short f2b(float f) {
    union { float f; unsigned int i; } v;
    v.f = f;
    return (unsigned short)((v.i + 0x7fffu + ((v.i >> 16) & 1u)) >> 16);  // RNE, finite-only
}

// Runtime input-dtype probe: bf16 emb data (N(0,0.02)) decodes to |v| < 0.15 for
// every u16; fp32 data has random low-mantissa words at even positions -> some
// finite |v| >= 1.0 with P ~ 1 - 2e-10. Uniform across the grid.
__device__ __forceinline__ bool detect_bf16(const unsigned short* p) {
    float mx = 0.f;
#pragma unroll
    for (int i = 0; i < 64; ++i) {
        const float a = fabsf(b2f(p[i]));
        if (a < 3.0e38f && a > mx) mx = a;   // NaN/Inf words skipped
    }
    return mx < 1.0f;
}

template <bool BF16IN>
__device__ __forceinline__ short8 load8(const void* base, long off) {
    if constexpr (BF16IN) {
        return *(const short8*)((const unsigned short*)base + off);
    } else {
        const float* p = (const float*)base + off;
        const floatx4 a = *(const floatx4*)p;
        const floatx4 c = *(const floatx4*)(p + 4);
        short8 r;
        r[0] = (short)f2b(a[0]); r[1] = (short)f2b(a[1]);
        r[2] = (short)f2b(a[2]); r[3] = (short)f2b(a[3]);
        r[4] = (short)f2b(c[0]); r[5] = (short)f2b(c[1]);
        r[6] = (short)f2b(c[2]); r[7] = (short)f2b(c[3]);
        return r;
    }
}
template <bool BF16IN>
__device__ __forceinline__ float loadS(const void* base, long off) {
    if constexpr (BF16IN) return b2f(((const unsigned short*)base)[off]);
    else return ((const float*)base)[off];
}

template <bool BF16IN>
__device__ __forceinline__ void body(
    const int* __restrict__ entity, const int* __restrict__ conn,
    const void* __restrict__ emb, const void* __restrict__ gw,
    const void* __restrict__ gwb, const void* __restrict__ gcnb,
    const void* __restrict__ w1, const void* __restrict__ b1,
    const void* __restrict__ w2, const void* __restrict__ b2,
    const void* __restrict__ temp, void* __restrict__ out,
    unsigned short* Xs, unsigned short* Ns,
    float* selfE, float* scoresS, float* attnS, float* gsumS)
{
    const int t = threadIdx.x;
    const int b = blockIdx.x;
    const int lane = t & 63;
    const int wave = t >> 6;
    const int l15 = lane & 15;
    const int quad = lane >> 4;

    // ---- P0: weight fragments into registers (NT-GEMM layout, m92/m97-verified) ----
    short8 Bfrag[8][2];
#pragma unroll
    for (int ft = 0; ft < 8; ++ft)
#pragma unroll
        for (int nn = 0; nn < 2; ++nn) {
            const int dcol = wave * 32 + nn * 16 + l15;
            Bfrag[ft][nn] = load8<BF16IN>(gw, dcol * 256 + ft * 32 + quad * 8);
        }
    short8 W1frag[4];
#pragma unroll
    for (int ft = 0; ft < 4; ++ft)
        W1frag[ft] = load8<BF16IN>(w1, (wave * 16 + l15) * 128 + ft * 32 + quad * 8);
    const float b1j = loadS<BF16IN>(b1, wave * 16 + l15);
    const float w2j = loadS<BF16IN>(w2, wave * 16 + l15);

    // ---- P0b: gather neighbor embeddings into LDS, zero pad rows, self emb ----
    {
        const int cbase = b * (KNBR * 2);
        for (int c = t; c < KNBR * 2 * 16; c += 256) {   // 100 rows x 16 chunks of 8 elems
            const int r = c >> 4, j = c & 15;
            const int sym = conn[cbase + r];             // r = k*2 + half
            const short8 v = load8<BF16IN>(emb, (long)sym * EMBED_D + j * 8);
            *(short8*)(Xs + (r >> 1) * XSTR + (r & 1) * 128 + j * 8) = v;
        }
        for (int i = t; i < (MROWS - KNBR) * 256; i += 256)
            Xs[(KNBR + (i >> 8)) * XSTR + (i & 255)] = 0;
        if (t < EMBED_D) selfE[t] = loadS<BF16IN>(emb, (long)entity[b] * EMBED_D + t);
        if (t < MROWS) gsumS[t] = loadS<BF16IN>(b2, 0);  // gate logit accumulator init
    }
    __syncthreads();

    // ---- P1: nbr = X(64x256) . W^T + gcn_w_b via mfma_f32_16x16x32_bf16 ----
    floatx4 acc[4][2];
    const floatx4 fzero = {0.f, 0.f, 0.f, 0.f};
#pragma unroll
    for (int m = 0; m < 4; ++m)
#pragma unroll
        for (int nn = 0; nn < 2; ++nn) acc[m][nn] = fzero;
#pragma unroll
    for (int ft = 0; ft < 8; ++ft) {
        short8 A[4];
#pragma unroll
        for (int m = 0; m < 4; ++m)
            A[m] = *(const short8*)(Xs + (m * 16 + l15) * XSTR + ft * 32 + quad * 8);
#pragma unroll
        for (int m = 0; m < 4; ++m)
#pragma unroll
            for (int nn = 0; nn < 2; ++nn)
                acc[m][nn] = __builtin_amdgcn_mfma_f32_16x16x32_bf16(A[m], Bfrag[ft][nn], acc[m][nn], 0, 0, 0);
    }
#pragma unroll
    for (int nn = 0; nn < 2; ++nn) {
        const int dcol = wave * 32 + nn * 16 + l15;
        const float bias = loadS<BF16IN>(gwb, dcol);
#pragma unroll
        for (int m = 0; m < 4; ++m)
#pragma unroll
            for (int r = 0; r < 4; ++r)
                Ns[(m * 16 + quad * 4 + r) * NSTR + dcol] = f2b(acc[m][nn][r] + bias);
    }
    __syncthreads();

    // ---- P2: scores[k] = (self . nbr[k]) / sqrt(128), 4 lanes per k ----
    {
        const int k = t >> 2, q = t & 3;
        float p = 0.f;
        if (k < KNBR) {
            const unsigned short* nr = Ns + k * NSTR + q * 32;
            const float* se = selfE + q * 32;
#pragma unroll
            for (int i = 0; i < 32; ++i) p += se[i] * b2f(nr[i]);
        }
        p += __shfl_xor(p, 1);
        p += __shfl_xor(p, 2);
        if (k < KNBR && q == 0) scoresS[k] = p * 0.088388347648318447f;  // 1/sqrt(128)
    }
    __syncthreads();

    // ---- softmax over k (wave 0; other waves fall through to P3) ----
    if (t < 64) {
        const float s = (t < KNBR) ? scoresS[t] : -INFINITY;
        float mx = s;
#pragma unroll
        for (int o = 32; o > 0; o >>= 1) mx = fmaxf(mx, __shfl_xor(mx, o));
        const float e = (t < KNBR) ? expf(s - mx) : 0.f;
        float sum = e;
#pragma unroll
        for (int o = 32; o > 0; o >>= 1) sum += __shfl_xor(sum, o);
        attnS[t] = e / sum;
    }

    // ---- P3: gate MLP: h = relu(nbr.w1^T + b1); logit = h.w2 ----
    floatx4 acc2[4];
#pragma unroll
    for (int m = 0; m < 4; ++m) acc2[m] = fzero;
#pragma unroll
    for (int ft = 0; ft < 4; ++ft) {
        short8 A2[4];
#pragma unroll
        for (int m = 0; m < 4; ++m)
            A2[m] = *(const short8*)(Ns + (m * 16 + l15) * NSTR + ft * 32 + quad * 8);
#pragma unroll
        for (int m = 0; m < 4; ++m)
            acc2[m] = __builtin_amdgcn_mfma_f32_16x16x32_bf16(A2[m], W1frag[ft], acc2[m], 0, 0, 0);
    }
#pragma unroll
    for (int m = 0; m < 4; ++m)
#pragma unroll
        for (int r = 0; r < 4; ++r) {
            float c = fmaxf(acc2[m][r] + b1j, 0.f) * w2j;
            c += __shfl_xor(c, 1);   // sum the 16 h-cols held across l15
            c += __shfl_xor(c, 2);
            c += __shfl_xor(c, 4);
            c += __shfl_xor(c, 8);
            if (l15 == 0) atomicAdd(&gsumS[m * 16 + quad * 4 + r], c);
        }
    __syncthreads();

    // ---- P4a: fold gate into attn ----
    if (t < KNBR) {
        const float invT = 1.0f / loadS<BF16IN>(temp, 0);
        const float g = 1.0f / (1.0f + expf(-gsumS[t] * invT));
        attnS[t] *= g;
    }
    __syncthreads();

    // ---- P4b: out[d] = tanh(max_k(attn*gate*nbr) + gcn_b) ----
    if (t < EMBED_D) {
        float mx = -INFINITY;
        for (int k = 0; k < KNBR; ++k)
            mx = fmaxf(mx, attnS[k] * b2f(Ns[k * NSTR + t]));
        const float o = tanhf(mx + loadS<BF16IN>(gcnb, t));
        if constexpr (BF16IN)
            ((unsigned short*)out)[(long)b * EMBED_D + t] = f2b(o);
        else
            ((float*)out)[(long)b * EMBED_D + t] = o;
    }
}

__global__ __launch_bounds__(256, 2)
void embed_matcher(const int* __restrict__ entity, const int* __restrict__ conn,
                   const void* __restrict__ emb, const void* __restrict__ gw,
                   const void* __restrict__ gwb, const void* __restrict__ gcnb,
                   const void* __restrict__ w1, const void* __restrict__ b1,
                   const void* __restrict__ w2, const void* __restrict__ b2,
                   const void* __restrict__ temp, void* __restrict__ out)
{
    __shared__ __align__(16) unsigned short Xs[MROWS * XSTR];
    __shared__ __align__(16) unsigned short Ns[MROWS * NSTR];
    __shared__ float selfE[EMBED_D];
    __shared__ float scoresS[MROWS];
    __shared__ float attnS[MROWS];
    __shared__ float gsumS[MROWS];

    // Uniform per-block dtype dispatch (identical data -> identical result on
    // every thread; barriers inside body stay convergent).
    if (detect_bf16((const unsigned short*)emb))
        body<true>(entity, conn, emb, gw, gwb, gcnb, w1, b1, w2, b2, temp, out,
                   Xs, Ns, selfE, scoresS, attnS, gsumS);
    else
        body<false>(entity, conn, emb, gw, gwb, gcnb, w1, b1, w2, b2, temp, out,
                    Xs, Ns, selfE, scoresS, attnS, gsumS);
}

extern "C" void kernel_launch(void* const* d_in, const int* in_sizes, int n_in,
                              void* d_out, int out_size, void* d_ws, size_t ws_size,
                              hipStream_t stream) {
    (void)n_in; (void)d_ws; (void)ws_size; (void)out_size;
    const int B = in_sizes[0];  // 8192
    embed_matcher<<<B, 256, 0, stream>>>(
        (const int*)d_in[0], (const int*)d_in[1],
        d_in[2], d_in[3], d_in[4], d_in[5],
        d_in[6], d_in[7], d_in[8], d_in[9], d_in[10],
        d_out);
}

// Round 3
// 306.415 us; speedup vs baseline: 1.3775x; 1.3775x over previous
//
#include <hip/hip_runtime.h>

#define EMBED_D 128
#define KNBR 50
#define MROWS 64      // padded neighbor rows for 16-row MFMA tiles
#define XSTR 264      // X row stride in bf16 elems (256 + 8 pad)
#define NSTR 136      // nbr row stride in bf16 elems (128 + 8 pad)

typedef __attribute__((ext_vector_type(8))) short short8;    // 8 bf16 = 4 VGPRs (MFMA A/B frag)
typedef __attribute__((ext_vector_type(4))) float floatx4;   // MFMA C/D frag

__device__ __forceinline__ float b2f(unsigned short u) {
    union { unsigned int i; float f; } v;
    v.i = ((unsigned int)u) << 16;
    return v.f;
}
__device__ __forceinline__ unsigned short f2b(float f) {
    union { float f; unsigned int i; } v;
    v.f = f;
    return (unsigned short)((v.i + 0x7fffu + ((v.i >> 16) & 1u)) >> 16);  // RNE, finite-only
}

// bf16 emb data (N(0,0.02)) decodes to |v| < 0.15 everywhere; fp32 data has
// random low-mantissa words -> some finite |v| >= 1.0 with P ~ 1-2e-10.
__device__ __forceinline__ bool detect_bf16(const unsigned short* p) {
    float mx = 0.f;
#pragma unroll
    for (int i = 0; i < 64; ++i) {
        const float a = fabsf(b2f(p[i]));
        if (a < 3.0e38f && a > mx) mx = a;
    }
    return mx < 1.0f;
}

// ---------------- preprocessing kernels ----------------

__global__ void detect_kernel(const unsigned short* __restrict__ emb, int* __restrict__ flag) {
    if (threadIdx.x == 0) *flag = detect_bf16(emb) ? 1 : 0;
}

__global__ void convert_emb_kernel(const void* __restrict__ src, unsigned short* __restrict__ dst,
                                   const int* __restrict__ flag, long n8) {
    const long i = (long)blockIdx.x * 256 + threadIdx.x;
    if (i >= n8) return;
    if (*flag) {   // already bf16: straight 16B copy
        *(short8*)(dst + i * 8) = *(const short8*)((const unsigned short*)src + i * 8);
    } else {       // fp32 -> bf16 RNE
        const float* p = (const float*)src + i * 8;
        const floatx4 a = *(const floatx4*)p;
        const floatx4 c = *(const floatx4*)(p + 4);
        short8 r;
        r[0] = (short)f2b(a[0]); r[1] = (short)f2b(a[1]);
        r[2] = (short)f2b(a[2]); r[3] = (short)f2b(a[3]);
        r[4] = (short)f2b(c[0]); r[5] = (short)f2b(c[1]);
        r[6] = (short)f2b(c[2]); r[7] = (short)f2b(c[3]);
        *(short8*)(dst + i * 8) = r;
    }
}

struct SmallTensors {
    const void* src[8];
    unsigned short* dst[8];
    int n[8];
};

__global__ void convert_small_kernel(SmallTensors st, const int* __restrict__ flag) {
    const bool isbf = (*flag != 0);
    const int gsz = gridDim.x * blockDim.x;
    const int gtid = blockIdx.x * blockDim.x + threadIdx.x;
#pragma unroll
    for (int ti = 0; ti < 8; ++ti) {
        const int n = st.n[ti];
        for (int i = gtid; i < n; i += gsz) {
            const float v = isbf ? b2f(((const unsigned short*)st.src[ti])[i])
                                 : ((const float*)st.src[ti])[i];
            st.dst[ti][i] = f2b(v);   // exact round-trip when already bf16
        }
    }
}

// ---------------- main kernel (bf16 staged inputs) ----------------

__global__ __launch_bounds__(256, 3)
void embed_matcher_fast(const int* __restrict__ entity, const int* __restrict__ conn,
                        const unsigned short* __restrict__ emb,
                        const unsigned short* __restrict__ gw,
                        const unsigned short* __restrict__ gwb,
                        const unsigned short* __restrict__ gcnb,
                        const unsigned short* __restrict__ w1,
                        const unsigned short* __restrict__ b1,
                        const unsigned short* __restrict__ w2,
                        const unsigned short* __restrict__ b2,
                        const unsigned short* __restrict__ temp,
                        const int* __restrict__ flag,
                        void* __restrict__ out)
{
    __shared__ __align__(16) unsigned short Xs[MROWS * XSTR];  // 33792 B
    __shared__ __align__(16) unsigned short Ns[MROWS * NSTR];  // 17408 B
    __shared__ float selfE[EMBED_D];
    __shared__ float scoresS[MROWS];
    __shared__ float attnS[MROWS];
    __shared__ float gsumS[MROWS];

    const int t = threadIdx.x;
    const int b = blockIdx.x;
    const int lane = t & 63;
    const int wave = t >> 6;
    const int l15 = lane & 15;
    const int quad = lane >> 4;

    // ---- P0: weight fragments into registers (NT-GEMM layout, m92/m97-verified) ----
    short8 Bfrag[8][2];
#pragma unroll
    for (int ft = 0; ft < 8; ++ft)
#pragma unroll
        for (int nn = 0; nn < 2; ++nn) {
            const int dcol = wave * 32 + nn * 16 + l15;
            Bfrag[ft][nn] = *(const short8*)(gw + dcol * 256 + ft * 32 + quad * 8);
        }
    short8 W1frag[4];
#pragma unroll
    for (int ft = 0; ft < 4; ++ft)
        W1frag[ft] = *(const short8*)(w1 + (wave * 16 + l15) * 128 + ft * 32 + quad * 8);
    const float b1j = b2f(b1[wave * 16 + l15]);
    const float w2j = b2f(w2[wave * 16 + l15]);

    // ---- P0b: gather neighbor embeddings into LDS, zero pad rows, self emb ----
    {
        const int cbase = b * (KNBR * 2);
        for (int c = t; c < KNBR * 2 * 16; c += 256) {   // 100 rows x 16 chunks of 8 elems
            const int r = c >> 4, j = c & 15;
            const int sym = conn[cbase + r];             // r = k*2 + half
            const short8 v = *(const short8*)(emb + (long)sym * EMBED_D + j * 8);
            *(short8*)(Xs + (r >> 1) * XSTR + (r & 1) * 128 + j * 8) = v;
        }
        const short8 z8 = {0, 0, 0, 0, 0, 0, 0, 0};
        for (int i = t; i < (MROWS - KNBR) * 32; i += 256)   // 14 rows x 32 chunks
            *(short8*)(Xs + (KNBR + (i >> 5)) * XSTR + (i & 31) * 8) = z8;
        if (t < EMBED_D) selfE[t] = b2f(emb[(long)entity[b] * EMBED_D + t]);
        if (t < MROWS) gsumS[t] = b2f(b2[0]);            // gate logit accumulator init
    }
    __syncthreads();

    // ---- P1: nbr = X(64x256) . W^T + gcn_w_b via mfma_f32_16x16x32_bf16 ----
    floatx4 acc[4][2];
    const floatx4 fzero = {0.f, 0.f, 0.f, 0.f};
#pragma unroll
    for (int m = 0; m < 4; ++m)
#pragma unroll
        for (int nn = 0; nn < 2; ++nn) acc[m][nn] = fzero;
#pragma unroll
    for (int ft = 0; ft < 8; ++ft) {
        short8 A[4];
#pragma unroll
        for (int m = 0; m < 4; ++m)
            A[m] = *(const short8*)(Xs + (m * 16 + l15) * XSTR + ft * 32 + quad * 8);
#pragma unroll
        for (int m = 0; m < 4; ++m)
#pragma unroll
            for (int nn = 0; nn < 2; ++nn)
                acc[m][nn] = __builtin_amdgcn_mfma_f32_16x16x32_bf16(A[m], Bfrag[ft][nn], acc[m][nn], 0, 0, 0);
    }
#pragma unroll
    for (int nn = 0; nn < 2; ++nn) {
        const int dcol = wave * 32 + nn * 16 + l15;
        const float bias = b2f(gwb[dcol]);
#pragma unroll
        for (int m = 0; m < 4; ++m)
#pragma unroll
            for (int r = 0; r < 4; ++r)
                Ns[(m * 16 + quad * 4 + r) * NSTR + dcol] = f2b(acc[m][nn][r] + bias);
    }
    __syncthreads();

    // ---- P2: scores[k] = (self . nbr[k]) / sqrt(128), 4 lanes per k ----
    {
        const int k = t >> 2, q = t & 3;
        float p = 0.f;
        if (k < KNBR) {
            const unsigned short* nr = Ns + k * NSTR + q * 32;
            const float* se = selfE + q * 32;
            short8 v0 = *(const short8*)(nr);
            short8 v1 = *(const short8*)(nr + 8);
            short8 v2 = *(const short8*)(nr + 16);
            short8 v3 = *(const short8*)(nr + 24);
#pragma unroll
            for (int i = 0; i < 8; ++i) {
                p += se[i]      * b2f((unsigned short)v0[i]);
                p += se[i + 8]  * b2f((unsigned short)v1[i]);
                p += se[i + 16] * b2f((unsigned short)v2[i]);
                p += se[i + 24] * b2f((unsigned short)v3[i]);
            }
        }
        p += __shfl_xor(p, 1);
        p += __shfl_xor(p, 2);
        if (k < KNBR && q == 0) scoresS[k] = p * 0.088388347648318447f;  // 1/sqrt(128)
    }
    __syncthreads();

    // ---- softmax over k (wave 0; other waves fall through to P3) ----
    if (t < 64) {
        const float s = (t < KNBR) ? scoresS[t] : -INFINITY;
        float mx = s;
#pragma unroll
        for (int o = 32; o > 0; o >>= 1) mx = fmaxf(mx, __shfl_xor(mx, o));
        const float e = (t < KNBR) ? expf(s - mx) : 0.f;
        float sum = e;
#pragma unroll
        for (int o = 32; o > 0; o >>= 1) sum += __shfl_xor(sum, o);
        attnS[t] = e / sum;
    }

    // ---- P3: gate MLP: h = relu(nbr.w1^T + b1); logit = h.w2 ----
    floatx4 acc2[4];
#pragma unroll
    for (int m = 0; m < 4; ++m) acc2[m] = fzero;
#pragma unroll
    for (int ft = 0; ft < 4; ++ft) {
        short8 A2[4];
#pragma unroll
        for (int m = 0; m < 4; ++m)
            A2[m] = *(const short8*)(Ns + (m * 16 + l15) * NSTR + ft * 32 + quad * 8);
#pragma unroll
        for (int m = 0; m < 4; ++m)
            acc2[m] = __builtin_amdgcn_mfma_f32_16x16x32_bf16(A2[m], W1frag[ft], acc2[m], 0, 0, 0);
    }
#pragma unroll
    for (int m = 0; m < 4; ++m)
#pragma unroll
        for (int r = 0; r < 4; ++r) {
            float c = fmaxf(acc2[m][r] + b1j, 0.f) * w2j;
            c += __shfl_xor(c, 1);   // sum the 16 h-cols held across l15
            c += __shfl_xor(c, 2);
            c += __shfl_xor(c, 4);
            c += __shfl_xor(c, 8);
            if (l15 == 0) atomicAdd(&gsumS[m * 16 + quad * 4 + r], c);
        }
    __syncthreads();

    // ---- P4a: fold gate into attn ----
    if (t < KNBR) {
        const float invT = 1.0f / b2f(temp[0]);
        const float g = 1.0f / (1.0f + expf(-gsumS[t] * invT));
        attnS[t] *= g;
    }
    __syncthreads();

    // ---- P4b: out[d] = tanh(max_k(attn*gate*nbr) + gcn_b) ----
    if (t < EMBED_D) {
        float mx = -INFINITY;
#pragma unroll
        for (int k = 0; k < KNBR; ++k)
            mx = fmaxf(mx, attnS[k] * b2f(Ns[k * NSTR + t]));
        const float o = tanhf(mx + b2f(gcnb[t]));
        if (*flag)
            ((unsigned short*)out)[(long)b * EMBED_D + t] = f2b(o);
        else
            ((float*)out)[(long)b * EMBED_D + t] = o;
    }
}

// ---------------- fallback (round-2 proven kernel, used only if ws too small) ----------------

template <bool BF16IN>
__device__ __forceinline__ short8 load8g(const void* base, long off) {
    if constexpr (BF16IN) {
        return *(const short8*)((const unsigned short*)base + off);
    } else {
        const float* p = (const float*)base + off;
        const floatx4 a = *(const floatx4*)p;
        const floatx4 c = *(const floatx4*)(p + 4);
        short8 r;
        r[0] = (short)f2b(a[0]); r[1] = (short)f2b(a[1]);
        r[2] = (short)f2b(a[2]); r[3] = (short)f2b(a[3]);
        r[4] = (short)f2b(c[0]); r[5] = (short)f2b(c[1]);
        r[6] = (short)f2b(c[2]); r[7] = (short)f2b(c[3]);
        return r;
    }
}
template <bool BF16IN>
__device__ __forceinline__ float loadSg(const void* base, long off) {
    if constexpr (BF16IN) return b2f(((const unsigned short*)base)[off]);
    else return ((const float*)base)[off];
}

template <bool BF16IN>
__device__ __forceinline__ void body_fb(
    const int* entity, const int* conn, const void* emb, const void* gw,
    const void* gwb, const void* gcnb, const void* w1, const void* b1,
    const void* w2, const void* b2, const void* temp, void* out,
    unsigned short* Xs, unsigned short* Ns,
    float* selfE, float* scoresS, float* attnS, float* gsumS)
{
    const int t = threadIdx.x, b = blockIdx.x;
    const int lane = t & 63, wave = t >> 6, l15 = lane & 15, quad = lane >> 4;
    short8 Bfrag[8][2];
#pragma unroll
    for (int ft = 0; ft < 8; ++ft)
#pragma unroll
        for (int nn = 0; nn < 2; ++nn)
            Bfrag[ft][nn] = load8g<BF16IN>(gw, (wave * 32 + nn * 16 + l15) * 256 + ft * 32 + quad * 8);
    short8 W1frag[4];
#pragma unroll
    for (int ft = 0; ft < 4; ++ft)
        W1frag[ft] = load8g<BF16IN>(w1, (wave * 16 + l15) * 128 + ft * 32 + quad * 8);
    const float b1j = loadSg<BF16IN>(b1, wave * 16 + l15);
    const float w2j = loadSg<BF16IN>(w2, wave * 16 + l15);
    {
        const int cbase = b * (KNBR * 2);
        for (int c = t; c < KNBR * 2 * 16; c += 256) {
            const int r = c >> 4, j = c & 15;
            const int sym = conn[cbase + r];
            *(short8*)(Xs + (r >> 1) * XSTR + (r & 1) * 128 + j * 8) =
                load8g<BF16IN>(emb, (long)sym * EMBED_D + j * 8);
        }
        for (int i = t; i < (MROWS - KNBR) * 256; i += 256)
            Xs[(KNBR + (i >> 8)) * XSTR + (i & 255)] = 0;
        if (t < EMBED_D) selfE[t] = loadSg<BF16IN>(emb, (long)entity[b] * EMBED_D + t);
        if (t < MROWS) gsumS[t] = loadSg<BF16IN>(b2, 0);
    }
    __syncthreads();
    floatx4 acc[4][2];
    const floatx4 fzero = {0.f, 0.f, 0.f, 0.f};
#pragma unroll
    for (int m = 0; m < 4; ++m)
#pragma unroll
        for (int nn = 0; nn < 2; ++nn) acc[m][nn] = fzero;
#pragma unroll
    for (int ft = 0; ft < 8; ++ft) {
        short8 A[4];
#pragma unroll
        for (int m = 0; m < 4; ++m)
            A[m] = *(const short8*)(Xs + (m * 16 + l15) * XSTR + ft * 32 + quad * 8);
#pragma unroll
        for (int m = 0; m < 4; ++m)
#pragma unroll
            for (int nn = 0; nn < 2; ++nn)
                acc[m][nn] = __builtin_amdgcn_mfma_f32_16x16x32_bf16(A[m], Bfrag[ft][nn], acc[m][nn], 0, 0, 0);
    }
#pragma unroll
    for (int nn = 0; nn < 2; ++nn) {
        const int dcol = wave * 32 + nn * 16 + l15;
        const float bias = loadSg<BF16IN>(gwb, dcol);
#pragma unroll
        for (int m = 0; m < 4; ++m)
#pragma unroll
            for (int r = 0; r < 4; ++r)
                Ns[(m * 16 + quad * 4 + r) * NSTR + dcol] = f2b(acc[m][nn][r] + bias);
    }
    __syncthreads();
    {
        const int k = t >> 2, q = t & 3;
        float p = 0.f;
        if (k < KNBR) {
            const unsigned short* nr = Ns + k * NSTR + q * 32;
            const float* se = selfE + q * 32;
#pragma unroll
            for (int i = 0; i < 32; ++i) p += se[i] * b2f(nr[i]);
        }
        p += __shfl_xor(p, 1);
        p += __shfl_xor(p, 2);
        if (k < KNBR && q == 0) scoresS[k] = p * 0.088388347648318447f;
    }
    __syncthreads();
    if (t < 64) {
        const float s = (t < KNBR) ? scoresS[t] : -INFINITY;
        float mx = s;
#pragma unroll
        for (int o = 32; o > 0; o >>= 1) mx = fmaxf(mx, __shfl_xor(mx, o));
        const float e = (t < KNBR) ? expf(s - mx) : 0.f;
        float sum = e;
#pragma unroll
        for (int o = 32; o > 0; o >>= 1) sum += __shfl_xor(sum, o);
        attnS[t] = e / sum;
    }
    floatx4 acc2[4];
#pragma unroll
    for (int m = 0; m < 4; ++m) acc2[m] = fzero;
#pragma unroll
    for (int ft = 0; ft < 4; ++ft) {
        short8 A2[4];
#pragma unroll
        for (int m = 0; m < 4; ++m)
            A2[m] = *(const short8*)(Ns + (m * 16 + l15) * NSTR + ft * 32 + quad * 8);
#pragma unroll
        for (int m = 0; m < 4; ++m)
            acc2[m] = __builtin_amdgcn_mfma_f32_16x16x32_bf16(A2[m], W1frag[ft], acc2[m], 0, 0, 0);
    }
#pragma unroll
    for (int m = 0; m < 4; ++m)
#pragma unroll
        for (int r = 0; r < 4; ++r) {
            float c = fmaxf(acc2[m][r] + b1j, 0.f) * w2j;
            c += __shfl_xor(c, 1); c += __shfl_xor(c, 2);
            c += __shfl_xor(c, 4); c += __shfl_xor(c, 8);
            if (l15 == 0) atomicAdd(&gsumS[m * 16 + quad * 4 + r], c);
        }
    __syncthreads();
    if (t < KNBR) {
        const float invT = 1.0f / loadSg<BF16IN>(temp, 0);
        attnS[t] *= 1.0f / (1.0f + expf(-gsumS[t] * invT));
    }
    __syncthreads();
    if (t < EMBED_D) {
        float mx = -INFINITY;
        for (int k = 0; k < KNBR; ++k)
            mx = fmaxf(mx, attnS[k] * b2f(Ns[k * NSTR + t]));
        const float o = tanhf(mx + loadSg<BF16IN>(gcnb, t));
        if constexpr (BF16IN)
            ((unsigned short*)out)[(long)b * EMBED_D + t] = f2b(o);
        else
            ((float*)out)[(long)b * EMBED_D + t] = o;
    }
}

__global__ __launch_bounds__(256, 2)
void embed_matcher_fallback(const int* entity, const int* conn, const void* emb,
                            const void* gw, const void* gwb, const void* gcnb,
                            const void* w1, const void* b1, const void* w2,
                            const void* b2, const void* temp, void* out)
{
    __shared__ __align__(16) unsigned short Xs[MROWS * XSTR];
    __shared__ __align__(16) unsigned short Ns[MROWS * NSTR];
    __shared__ float selfE[EMBED_D];
    __shared__ float scoresS[MROWS];
    __shared__ float attnS[MROWS];
    __shared__ float gsumS[MROWS];
    if (detect_bf16((const unsigned short*)emb))
        body_fb<true>(entity, conn, emb, gw, gwb, gcnb, w1, b1, w2, b2, temp, out,
                      Xs, Ns, selfE, scoresS, attnS, gsumS);
    else
        body_fb<false>(entity, conn, emb, gw, gwb, gcnb, w1, b1, w2, b2, temp, out,
                       Xs, Ns, selfE, scoresS, attnS, gsumS);
}

// ---------------- launcher ----------------

static inline size_t align256(size_t x) { return (x + 255) & ~(size_t)255; }

extern "C" void kernel_launch(void* const* d_in, const int* in_sizes, int n_in,
                              void* d_out, int out_size, void* d_ws, size_t ws_size,
                              hipStream_t stream) {
    (void)n_in; (void)out_size;
    const int B = in_sizes[0];  // 8192

    // ws layout: bf16 copies of all float tensors + dtype flag
    const long n_emb = in_sizes[2];
    size_t off[9], cur = 0;
    const int ns[8] = {in_sizes[3], in_sizes[4], in_sizes[5], in_sizes[6],
                       in_sizes[7], in_sizes[8], in_sizes[9], in_sizes[10]};
    off[0] = 0; cur = align256((size_t)n_emb * 2);                      // emb
    for (int i = 0; i < 8; ++i) { off[i + 1] = cur; cur = align256(cur + (size_t)ns[i] * 2); }
    const size_t off_flag = cur; cur += 256;

    if (ws_size < cur) {
        // not enough scratch: proven single-kernel path
        embed_matcher_fallback<<<B, 256, 0, stream>>>(
            (const int*)d_in[0], (const int*)d_in[1],
            d_in[2], d_in[3], d_in[4], d_in[5],
            d_in[6], d_in[7], d_in[8], d_in[9], d_in[10], d_out);
        return;
    }

    char* ws = (char*)d_ws;
    int* flag = (int*)(ws + off_flag);
    unsigned short* emb_b = (unsigned short*)(ws + off[0]);

    detect_kernel<<<1, 64, 0, stream>>>((const unsigned short*)d_in[2], flag);

    const long n8 = n_emb / 8;   // 12,800,128 divisible by 8
    convert_emb_kernel<<<(int)((n8 + 255) / 256), 256, 0, stream>>>(d_in[2], emb_b, flag, n8);

    SmallTensors st;
    for (int i = 0; i < 8; ++i) {
        st.src[i] = d_in[3 + i];
        st.dst[i] = (unsigned short*)(ws + off[i + 1]);
        st.n[i] = ns[i];
    }
    convert_small_kernel<<<16, 256, 0, stream>>>(st, flag);

    embed_matcher_fast<<<B, 256, 0, stream>>>(
        (const int*)d_in[0], (const int*)d_in[1],
        emb_b,
        (const unsigned short*)(ws + off[1]),   // gw
        (const unsigned short*)(ws + off[2]),   // gwb
        (const unsigned short*)(ws + off[3]),   // gcnb
        (const unsigned short*)(ws + off[4]),   // w1
        (const unsigned short*)(ws + off[5]),   // b1
        (const unsigned short*)(ws + off[6]),   // w2
        (const unsigned short*)(ws + off[7]),   // b2
        (const unsigned short*)(ws + off[8]),   // temp
        flag, d_out);
}